// Round 13
// baseline (96.360 us; speedup 1.0000x reference)
//
#include <hip/hip_runtime.h>
#include <math.h>

// Density loss: B=8, N=2048, C=3, K=16 (includes self-distance 0).
// Structure = R12 verified kernel (fastest passing: total 90.3us; knn ~37us,
// below the harness's 40us/256MiB workspace-poison fill which dominates).
// R13: final_reduce dispatch FUSED via fence-free atomic handoff:
//  - each block atomicAdd()s its partial into acc[seg] (device-scope atomic,
//    executes at coherence point -> NO cache flush, unlike R7's agent-scope
//    release stores whose per-block buffer_wbl2 cost +33us);
//  - ordering acc-add -> ticket-add enforced by a DATA DEPENDENCY on the
//    returned old value (compiler must drain vmcnt), not by a fence;
//  - ticket zeroed by hipMemsetAsync each launch (proven in R7), so winner
//    (old == NBLOCKS-1) is the true last arrival; it reads the 16
//    accumulators with atomic reads and writes the MSE.
// fp add-order wobble from atomic accumulation: ~few ulps of ~600-magnitude
// sums -> ~1e-12 in the final scalar, far under the 8.7e-7 threshold.
// Everything else byte-identical to R12:
//  - 1024 blocks (one full generation, 4 blocks/CU), 2 items/block staged
//    once; per wave 2 queries; seeded+early-exit ballot bisections; group
//    compaction via ballot+mbcnt; DPP wave sums; exact-16 bit bisection.
// Fallback (group-scratch overflow, ~never): exact 16-round extraction.

#define NPTS 2048
#define KSEL 16
#define WAVES_PER_BLOCK 8
#define BLOCK (WAVES_PER_BLOCK * 64)          // 512
#define PTS_PER_ITEM (WAVES_PER_BLOCK * 2)    // 16 queries per item
#define NITEMS_PER_TB (NPTS / PTS_PER_ITEM)   // 128 items per (t,b)
#define NBLOCKS (2 * 8 * (NITEMS_PER_TB / 2)) // 1024, 2 items per block

__device__ __forceinline__ int mbcnt64(unsigned long long m) {
  // popcount of m restricted to lanes strictly below this lane.
  return __builtin_amdgcn_mbcnt_hi(
      (unsigned)(m >> 32), __builtin_amdgcn_mbcnt_lo((unsigned)m, 0u));
}

// f32 add of DPP-moved operand. CTRL/ROW_MASK are template (literal)
// constants as required by the builtin. old=0 + bound_ctrl=true => lanes
// with disabled/out-of-range sources add 0 (identity for summation).
template <int CTRL, int ROW_MASK>
__device__ __forceinline__ float dpp_add(float v) {
  const int t = __builtin_amdgcn_update_dpp(0, __float_as_int(v), CTRL,
                                            ROW_MASK, 0xf, true);
  return v + __int_as_float(t);
}

// Canonical gfx9 wave64 sum: row_shr 1/2/4/8 then row_bcast 15/31;
// total lands in lane 63. VALU-only, no DS pipe.
__device__ __forceinline__ float wave_sum_dpp(float v) {
  v = dpp_add<0x111, 0xf>(v);  // row_shr:1
  v = dpp_add<0x112, 0xf>(v);  // row_shr:2
  v = dpp_add<0x114, 0xf>(v);  // row_shr:4
  v = dpp_add<0x118, 0xf>(v);  // row_shr:8
  v = dpp_add<0x142, 0xa>(v);  // row_bcast:15 -> rows 1,3
  v = dpp_add<0x143, 0xc>(v);  // row_bcast:31 -> rows 2,3
  return __int_as_float(__builtin_amdgcn_readlane(__float_as_int(v), 63));
}

__device__ __forceinline__ float dist2(float px, float py, float pz,
                                       float cx, float cy, float cz) {
  float dx = px - cx, dy = py - cy, dz = pz - cz;
  return fmaf(dz, dz, fmaf(dy, dy, dx * dx));
}

// Redistribute qualifying groups (gm <= thr) one-per-lane via scrI; each
// active lane recomputes its group's 4 distances (bitwise-identical fmaf).
// Inactive lanes get INF. ok=false (wave-uniform) iff >64 qualifying groups.
__device__ __forceinline__ void gather_candidates(
    const float (&gm)[8], float thr, float px, float py, float pz, int lane,
    const float* xs, const float* ys, const float* zs, int* scrI, bool& ok,
    float& d0, float& d1, float& d2, float& d3) {
  unsigned qmask = 0u;
  int qg = 0;
  #pragma unroll
  for (int m = 0; m < 8; ++m) {
    const bool q = gm[m] <= thr;
    qmask |= q ? (1u << m) : 0u;
    qg += q ? 1 : 0;
  }
  // Exclusive prefix + total of qg (0..8) via bit-plane ballots.
  const unsigned long long b0 = __ballot((qg & 1) != 0);
  const unsigned long long b1 = __ballot((qg & 2) != 0);
  const unsigned long long b2 = __ballot((qg & 4) != 0);
  const unsigned long long b3 = __ballot((qg & 8) != 0);
  const int pre =
      mbcnt64(b0) + 2 * mbcnt64(b1) + 4 * mbcnt64(b2) + 8 * mbcnt64(b3);
  const int tot = __popcll(b0) + 2 * __popcll(b1) + 4 * __popcll(b2) +
                  8 * __popcll(b3);
  ok = (tot <= 64);
  if (ok) {
    // Scatter qualifying group ids. Fast path: first 2 bits per lane
    // (wave-max qg <= 2 almost always); cold tail covers qg in [3,8].
    int pos = pre;
    unsigned mrem = qmask;
    #pragma unroll
    for (int k = 0; k < 2; ++k) {
      const bool w = (mrem != 0u);
      const int m = __ffs(mrem) - 1;
      if (w) scrI[pos] = (lane << 3) | m;
      pos += w ? 1 : 0;
      mrem = w ? (mrem & (mrem - 1u)) : 0u;
    }
    if (__ballot(mrem != 0u) != 0ull) {  // wave-uniform, rare
      #pragma unroll
      for (int k = 0; k < 6; ++k) {
        const bool w = (mrem != 0u);
        const int m = __ffs(mrem) - 1;
        if (w) scrI[pos] = (lane << 3) | m;
        pos += w ? 1 : 0;
        mrem = w ? (mrem & (mrem - 1u)) : 0u;
      }
    }
  }
  d0 = INFINITY; d1 = INFINITY; d2 = INFINITY; d3 = INFINITY;
  if (ok && lane < tot) {
    const int id = scrI[lane];
    const int o = ((id >> 3) << 2) + ((id & 7) << 8);
    const float4 cx4 = *(const float4*)&xs[o];
    const float4 cy4 = *(const float4*)&ys[o];
    const float4 cz4 = *(const float4*)&zs[o];
    d0 = dist2(px, py, pz, cx4.x, cy4.x, cz4.x);
    d1 = dist2(px, py, pz, cx4.y, cy4.y, cz4.y);
    d2 = dist2(px, py, pz, cx4.z, cy4.z, cz4.z);
    d3 = dist2(px, py, pz, cx4.w, cy4.w, cz4.w);
  }
}

// Exact fallback (~never): 16 extraction rounds, recompute from LDS.
__device__ float fallback_sum16(float px, float py, float pz, int lane,
                                const float* xs, const float* ys,
                                const float* zs) {
  float s = 0.f;
  unsigned consumed = 0u;
  #pragma unroll 1
  for (int r = 0; r < KSEL; ++r) {
    float bv = INFINITY;
    int bi = 0;
    #pragma unroll
    for (int m = 0; m < 8; ++m) {
      const int o = (lane << 2) + (m << 8);
      const float4 cx4 = *(const float4*)&xs[o];
      const float4 cy4 = *(const float4*)&ys[o];
      const float4 cz4 = *(const float4*)&zs[o];
      float dd;
      bool okb;
      dd = dist2(px, py, pz, cx4.x, cy4.x, cz4.x);
      okb = (((consumed >> ((m << 2) + 0)) & 1u) == 0u) && (dd < bv);
      bv = okb ? dd : bv; bi = okb ? ((m << 2) + 0) : bi;
      dd = dist2(px, py, pz, cx4.y, cy4.y, cz4.y);
      okb = (((consumed >> ((m << 2) + 1)) & 1u) == 0u) && (dd < bv);
      bv = okb ? dd : bv; bi = okb ? ((m << 2) + 1) : bi;
      dd = dist2(px, py, pz, cx4.z, cy4.z, cz4.z);
      okb = (((consumed >> ((m << 2) + 2)) & 1u) == 0u) && (dd < bv);
      bv = okb ? dd : bv; bi = okb ? ((m << 2) + 2) : bi;
      dd = dist2(px, py, pz, cx4.w, cy4.w, cz4.w);
      okb = (((consumed >> ((m << 2) + 3)) & 1u) == 0u) && (dd < bv);
      bv = okb ? dd : bv; bi = okb ? ((m << 2) + 3) : bi;
    }
    int bl = lane;
    #pragma unroll
    for (int ofs = 32; ofs >= 1; ofs >>= 1) {
      float ov = __shfl_xor(bv, ofs);
      int ol = __shfl_xor(bl, ofs);
      bool take = (ov < bv) || (ov == bv && ol < bl);
      bv = take ? ov : bv;
      bl = take ? ol : bl;
    }
    s += bv;
    if (lane == bl) consumed |= (1u << bi);
  }
  return s;
}

// Process one 16-query work item (group g): this wave's two queries.
// Returns sumA+sumB. scrI0/scrI1 are this wave's private 64-entry scratches.
__device__ float item_pair_sum(int g, int wave, int lane, const float* xs,
                               const float* ys, const float* zs, int* scrI0,
                               int* scrI1) {
  const int iA = g * PTS_PER_ITEM + wave * 2;
  const int iB = iA + 1;
  const float pax = xs[iA], pay = ys[iA], paz = zs[iA];
  const float pbx = xs[iB], pby = ys[iB], pbz = zs[iB];

  // Distance pass: candidate index = 4*lane + j + 256*m. Keep group mins.
  float gmA[8], gmB[8];
  #pragma unroll
  for (int m = 0; m < 8; ++m) {
    const int o = (lane << 2) + (m << 8);
    const float4 cx4 = *(const float4*)&xs[o];
    const float4 cy4 = *(const float4*)&ys[o];
    const float4 cz4 = *(const float4*)&zs[o];
    float a0 = dist2(pax, pay, paz, cx4.x, cy4.x, cz4.x);
    float a1 = dist2(pax, pay, paz, cx4.y, cy4.y, cz4.y);
    float a2 = dist2(pax, pay, paz, cx4.z, cy4.z, cz4.z);
    float a3 = dist2(pax, pay, paz, cx4.w, cy4.w, cz4.w);
    gmA[m] = fminf(fminf(a0, a1), fminf(a2, a3));
    float b0 = dist2(pbx, pby, pbz, cx4.x, cy4.x, cz4.x);
    float b1 = dist2(pbx, pby, pbz, cx4.y, cy4.y, cz4.y);
    float b2 = dist2(pbx, pby, pbz, cx4.z, cy4.z, cz4.z);
    float b3 = dist2(pbx, pby, pbz, cx4.w, cy4.w, cz4.w);
    gmB[m] = fminf(fminf(b0, b1), fminf(b2, b3));
  }
  float lminA = gmA[0], lminB = gmB[0];
  #pragma unroll
  for (int m = 1; m < 8; ++m) {
    lminA = fminf(lminA, gmA[m]);
    lminB = fminf(lminB, gmB[m]);
  }

  // Threshold bisection on lane-mins (uint-order-isomorphic for nonneg
  // floats), interleaved A/B, early-exit when count lands in [16,24].
  // Bounds seeded [1/512, 0.25] with guard ballots; invariants preserved:
  // count(<=hi) >= 16 always, count(<=lo) < 16 always.
  const unsigned uA = __float_as_uint(lminA);
  const unsigned uB = __float_as_uint(lminB);
  const unsigned SH = 0x3E800000u;  // 0.25f
  const unsigned SL = 0x3B000000u;  // 1/512
  unsigned loA = 0u, hiA = 0x7F800000u, loB = 0u, hiB = 0x7F800000u;
  bool thA = false, thB = false;
  {
    const int cA = __popcll(__ballot(uA <= SH));
    const int cB = __popcll(__ballot(uB <= SH));
    if (cA >= KSEL) { hiA = SH; thA = (cA <= 24); }
    if (cB >= KSEL) { hiB = SH; thB = (cB <= 24); }
    const int dA = __popcll(__ballot(uA <= SL));
    const int dB = __popcll(__ballot(uB <= SL));
    if (dA < KSEL) loA = SL;
    if (dB < KSEL) loB = SL;
  }
  #pragma unroll 1
  for (int r = 0; r < 16; ++r) {
    if (thA && thB) break;  // wave-uniform
    const unsigned midA = (loA + hiA) >> 1;
    const unsigned midB = (loB + hiB) >> 1;
    const int cA = __popcll(__ballot(uA <= midA));
    const int cB = __popcll(__ballot(uB <= midB));
    if (!thA) {
      const bool gA = cA >= KSEL;
      hiA = gA ? midA : hiA;
      loA = gA ? loA : midA;
      thA = (cA >= KSEL) && (cA <= 24);
    }
    if (!thB) {
      const bool gB = cB >= KSEL;
      hiB = gB ? midB : hiB;
      loB = gB ? loB : midB;
      thB = (cB >= KSEL) && (cB <= 24);
    }
  }
  const float thrA = __uint_as_float(hiA);
  const float thrB = __uint_as_float(hiB);

  // Gather candidates: <=4 register distances per lane per query. Candidate
  // multiset contains every distance <= thr (>=16 of them), so its 16
  // smallest equal the true 16 smallest.
  bool okA, okB;
  float a0, a1, a2, a3, b0, b1, b2, b3;
  gather_candidates(gmA, thrA, pax, pay, paz, lane, xs, ys, zs, scrI0, okA,
                    a0, a1, a2, a3);
  gather_candidates(gmB, thrB, pbx, pby, pbz, lane, xs, ys, zs, scrI1, okB,
                    b0, b1, b2, b3);

  // Exact 16-smallest sum via interleaved early-exit bit bisection on
  // w = bits(d)+1 (monotone; w>=1; INF -> 0x7F800001).
  // Seeds: ehi = bits(thr)+1 (count >= 16 guaranteed by gather
  // completeness); elo = bits(thr) - 6 exponent steps, guarded.
  // Exit when count==16 (sum values w <= mid directly) or hi == lo+1
  // (t* = value(hi-1); sum = sum(w<=lo) + (16 - count(w<=lo)) * t*).
  const unsigned wa0 = __float_as_uint(a0) + 1u, wa1 = __float_as_uint(a1) + 1u;
  const unsigned wa2 = __float_as_uint(a2) + 1u, wa3 = __float_as_uint(a3) + 1u;
  const unsigned wb0 = __float_as_uint(b0) + 1u, wb1 = __float_as_uint(b1) + 1u;
  const unsigned wb2 = __float_as_uint(b2) + 1u, wb3 = __float_as_uint(b3) + 1u;
  unsigned eloA = 0u, ehiA = hiA + 1u;
  unsigned eloB = 0u, ehiB = hiB + 1u;
  {
    const unsigned esA = (hiA >= (6u << 23)) ? hiA - (6u << 23) : 0u;
    const unsigned esB = (hiB >= (6u << 23)) ? hiB - (6u << 23) : 0u;
    const int nA = __popcll(__ballot(wa0 <= esA)) +
                   __popcll(__ballot(wa1 <= esA)) +
                   __popcll(__ballot(wa2 <= esA)) +
                   __popcll(__ballot(wa3 <= esA));
    const int nB = __popcll(__ballot(wb0 <= esB)) +
                   __popcll(__ballot(wb1 <= esB)) +
                   __popcll(__ballot(wb2 <= esB)) +
                   __popcll(__ballot(wb3 <= esB));
    if (nA < KSEL) eloA = esA;
    if (nB < KSEL) eloB = esB;
  }
  bool hA = false, hB = false;      // hit count==16 (sum directly via sel)
  unsigned sA = 0u, sB = 0u;
  #pragma unroll 1
  for (int r = 0; r < 32; ++r) {
    const bool needA = okA && !hA && (ehiA > eloA + 1u);
    const bool needB = okB && !hB && (ehiB > eloB + 1u);
    if (!(needA || needB)) break;  // wave-uniform
    const unsigned midA = (eloA + ehiA) >> 1;
    const unsigned midB = (eloB + ehiB) >> 1;
    const int cA = __popcll(__ballot(wa0 <= midA)) +
                   __popcll(__ballot(wa1 <= midA)) +
                   __popcll(__ballot(wa2 <= midA)) +
                   __popcll(__ballot(wa3 <= midA));
    const int cB = __popcll(__ballot(wb0 <= midB)) +
                   __popcll(__ballot(wb1 <= midB)) +
                   __popcll(__ballot(wb2 <= midB)) +
                   __popcll(__ballot(wb3 <= midB));
    if (needA) {
      if (cA >= KSEL) ehiA = midA; else eloA = midA;
      if (cA == KSEL) { hA = true; sA = midA; }
    }
    if (needB) {
      if (cB >= KSEL) ehiB = midB; else eloB = midB;
      if (cB == KSEL) { hB = true; sB = midB; }
    }
  }
  float extraA = 0.f, extraB = 0.f;
  if (okA && !hA) {
    sA = eloA;
    const int nlo = __popcll(__ballot(wa0 <= eloA)) +
                    __popcll(__ballot(wa1 <= eloA)) +
                    __popcll(__ballot(wa2 <= eloA)) +
                    __popcll(__ballot(wa3 <= eloA));
    extraA = (float)(KSEL - nlo) * __uint_as_float(ehiA - 1u);
  }
  if (okB && !hB) {
    sB = eloB;
    const int nlo = __popcll(__ballot(wb0 <= eloB)) +
                    __popcll(__ballot(wb1 <= eloB)) +
                    __popcll(__ballot(wb2 <= eloB)) +
                    __popcll(__ballot(wb3 <= eloB));
    extraB = (float)(KSEL - nlo) * __uint_as_float(ehiB - 1u);
  }
  float ca = 0.f, cb = 0.f;
  if (okA) {
    ca = ((wa0 <= sA) ? a0 : 0.f) + ((wa1 <= sA) ? a1 : 0.f) +
         ((wa2 <= sA) ? a2 : 0.f) + ((wa3 <= sA) ? a3 : 0.f);
  }
  if (okB) {
    cb = ((wb0 <= sB) ? b0 : 0.f) + ((wb1 <= sB) ? b1 : 0.f) +
         ((wb2 <= sB) ? b2 : 0.f) + ((wb3 <= sB) ? b3 : 0.f);
  }
  // Wave sums via DPP cascade (no DS-pipe traffic, no bpermute latency).
  const float caT = wave_sum_dpp(ca);
  const float cbT = wave_sum_dpp(cb);
  float sumA = caT + extraA;
  float sumB = cbT + extraB;
  if (!okA) sumA = fallback_sum16(pax, pay, paz, lane, xs, ys, zs);
  if (!okB) sumB = fallback_sum16(pbx, pby, pbz, lane, xs, ys, zs);
  return sumA + sumB;
}

__global__ __launch_bounds__(BLOCK) void knn_density_kernel(
    const float* __restrict__ seed, const float* __restrict__ gt,
    float* __restrict__ acc, unsigned* __restrict__ ticket,
    float* __restrict__ out) {
  __shared__ float xs[NPTS];
  __shared__ float ys[NPTS];
  __shared__ float zs[NPTS];
  __shared__ int scrI[WAVES_PER_BLOCK][2][64];
  __shared__ float bsums[WAVES_PER_BLOCK];
  __shared__ float red[16];
  __shared__ int winflag;

  const int bid = blockIdx.x;        // 1024 blocks (one full generation)
  const int t = bid >> 9;            // tensor: 0=seed 1=gt
  const int b = (bid >> 6) & 7;      // batch
  const int j = bid & 63;            // item-pair index: items 2j, 2j+1
  const float* base = (t == 0 ? seed : gt) + b * NPTS * 3;

  const int tid = threadIdx.x;

  // Stage SoA once for both items: thread tid handles points 4*tid..4*tid+3.
  {
    const float4* src = (const float4*)base;
    float4 f0 = src[3 * tid + 0];
    float4 f1 = src[3 * tid + 1];
    float4 f2 = src[3 * tid + 2];
    *(float4*)&xs[4 * tid] = make_float4(f0.x, f0.w, f1.z, f2.y);
    *(float4*)&ys[4 * tid] = make_float4(f0.y, f1.x, f1.w, f2.z);
    *(float4*)&zs[4 * tid] = make_float4(f0.z, f1.y, f2.x, f2.w);
  }
  __syncthreads();

  const int wave = tid >> 6;
  const int lane = tid & 63;

  // Two items back-to-back; scrI is wave-private so no barrier between.
  float wsum = item_pair_sum(2 * j + 0, wave, lane, xs, ys, zs,
                             &scrI[wave][0][0], &scrI[wave][1][0]);
  wsum += item_pair_sum(2 * j + 1, wave, lane, xs, ys, zs,
                        &scrI[wave][0][0], &scrI[wave][1][0]);

  if (lane == 0) bsums[wave] = wsum;
  __syncthreads();
  if (tid == 0) {
    float s = 0.f;
    #pragma unroll
    for (int w = 0; w < WAVES_PER_BLOCK; ++w) s += bsums[w];
    // Fence-free handoff: device-scope atomicAdd executes at the coherence
    // point (nothing cached to flush). acc[] and ticket are zeroed by
    // kernel_launch's memset each launch.
    const int seg = bid >> 6;  // t*8 + b
    const float old = atomicAdd(&acc[seg], s);
    // Data dependency + memory clobber: the acc atomic must complete
    // (vmcnt drained for `old`) before the ticket RMW issues. This is the
    // producer->winner ordering WITHOUT any agent-scope release fence
    // (R7's per-block buffer_wbl2 cost +33us).
    asm volatile("" ::"v"(old) : "memory");
    const unsigned tk = atomicAdd(ticket, 1u);
    winflag = (tk == (unsigned)(NBLOCKS - 1)) ? 1 : 0;
  }
  __syncthreads();

  if (winflag) {  // block-uniform: true last arrival reduces 16 accumulators
    if (tid < 16) {
      // Atomic read (add 0) at the coherence point sees all completed adds;
      // every producer's add completed before its ticket, and all tickets
      // precede ours.
      red[tid] = atomicAdd(&acc[tid], 0.0f);
    }
    __syncthreads();
    if (tid == 0) {
      const float scale = 1.f / (2048.f * 16.f);  // mean over pts, mean over k
      float accv = 0.f;
      #pragma unroll
      for (int bb = 0; bb < 8; ++bb) {
        float diff = (red[bb] - red[8 + bb]) * scale;
        accv += diff * diff;
      }
      out[0] = accv * 0.125f;
    }
  }
}

extern "C" void kernel_launch(void* const* d_in, const int* in_sizes, int n_in,
                              void* d_out, int out_size, void* d_ws, size_t ws_size,
                              hipStream_t stream) {
  const float* seed = (const float*)d_in[0];
  const float* gt = (const float*)d_in[1];
  float* out = (float*)d_out;
  float* ws = (float*)d_ws;
  float* acc = ws;                        // 16 floats
  unsigned* ticket = (unsigned*)(ws + 16);  // 1 uint

  // Zero accumulators + ticket every launch (graph-capturable async memset;
  // 68 bytes). Makes the winner the true last arrival and the atomicAdd
  // accumulation start from 0 regardless of workspace poison.
  hipMemsetAsync(ws, 0, 16 * sizeof(float) + sizeof(unsigned), stream);
  knn_density_kernel<<<NBLOCKS, BLOCK, 0, stream>>>(seed, gt, acc, ticket, out);
}

// Round 14
// 90.017 us; speedup vs baseline: 1.0705x; 1.0705x over previous
//
#include <hip/hip_runtime.h>
#include <math.h>

// Density loss: B=8, N=2048, C=3, K=16 (includes self-distance 0).
// FINAL STRUCTURE = R12 verified kernel (best passing: total 90.3us).
// R13's fused variant was correct but +6us (1024 serialized ticket RMWs at
// the coherence point + winner tail + extra memset dispatch) -> fusion is
// permanently dead (3 design points measured: R7 agent-fence +33us, R4/R6
// mid-stream-winner bug, R13 fence-free atomics +5us). Two-kernel handoff
// through the kernel boundary is the cheapest correct option.
// Breakdown: ~40us harness workspace-poison fill (83% peak HBM, untouchable)
// + ~37us knn (latency-bound: 46% VALUBusy, 1.3% HBM) + ~3us final + gaps.
//
// knn kernel: one wave per TWO query points (Q=2); each BLOCK processes TWO
// work items (adjacent 16-point groups, same (t,b)) so the 24KB staging is
// paid once per 2 items and the grid is EXACTLY one resident generation
// (1024 blocks = 4 blocks/CU x 256 CU).
// Selection machinery (verified through R5/R11/R12, absmax 0):
//   1) distance pass keeps per-group-of-4 mins gm[8] per query.
//   2) thr >= true d16 via interleaved ballot bisection on lane-mins,
//      bounds seeded [1/512, 0.25] with guard ballots (invariant-safe),
//      early-exit when count in [16,24].
//   3) group compaction via ballot+mbcnt bit-planes; redistribute 1 group/
//      lane, recompute its 4 distances. Values > thr kept (harmless).
//   4) exact sum of 16 smallest via interleaved A/B early-exit bit bisection
//      seeded ehi=bits(thr)+1, guarded elo=thr*2^-6; terminates on
//      count==16 or hi==lo+1. DPP wave sums (no DS-pipe traffic).
// Fallback (group-scratch overflow, ~never): exact 16-round extraction.
// Kernel 2: 1024 block partials -> MSE.

#define NPTS 2048
#define KSEL 16
#define WAVES_PER_BLOCK 8
#define BLOCK (WAVES_PER_BLOCK * 64)          // 512
#define PTS_PER_ITEM (WAVES_PER_BLOCK * 2)    // 16 queries per item
#define NITEMS_PER_TB (NPTS / PTS_PER_ITEM)   // 128 items per (t,b)
#define NBLOCKS (2 * 8 * (NITEMS_PER_TB / 2)) // 1024, 2 items per block

__device__ __forceinline__ int mbcnt64(unsigned long long m) {
  // popcount of m restricted to lanes strictly below this lane.
  return __builtin_amdgcn_mbcnt_hi(
      (unsigned)(m >> 32), __builtin_amdgcn_mbcnt_lo((unsigned)m, 0u));
}

// f32 add of DPP-moved operand. CTRL/ROW_MASK are template (literal)
// constants as required by the builtin. old=0 + bound_ctrl=true => lanes
// with disabled/out-of-range sources add 0 (identity for summation).
template <int CTRL, int ROW_MASK>
__device__ __forceinline__ float dpp_add(float v) {
  const int t = __builtin_amdgcn_update_dpp(0, __float_as_int(v), CTRL,
                                            ROW_MASK, 0xf, true);
  return v + __int_as_float(t);
}

// Canonical gfx9 wave64 sum: row_shr 1/2/4/8 then row_bcast 15/31;
// total lands in lane 63. VALU-only, no DS pipe.
__device__ __forceinline__ float wave_sum_dpp(float v) {
  v = dpp_add<0x111, 0xf>(v);  // row_shr:1
  v = dpp_add<0x112, 0xf>(v);  // row_shr:2
  v = dpp_add<0x114, 0xf>(v);  // row_shr:4
  v = dpp_add<0x118, 0xf>(v);  // row_shr:8
  v = dpp_add<0x142, 0xa>(v);  // row_bcast:15 -> rows 1,3
  v = dpp_add<0x143, 0xc>(v);  // row_bcast:31 -> rows 2,3
  return __int_as_float(__builtin_amdgcn_readlane(__float_as_int(v), 63));
}

__device__ __forceinline__ float dist2(float px, float py, float pz,
                                       float cx, float cy, float cz) {
  float dx = px - cx, dy = py - cy, dz = pz - cz;
  return fmaf(dz, dz, fmaf(dy, dy, dx * dx));
}

// Redistribute qualifying groups (gm <= thr) one-per-lane via scrI; each
// active lane recomputes its group's 4 distances (bitwise-identical fmaf).
// Inactive lanes get INF. ok=false (wave-uniform) iff >64 qualifying groups.
__device__ __forceinline__ void gather_candidates(
    const float (&gm)[8], float thr, float px, float py, float pz, int lane,
    const float* xs, const float* ys, const float* zs, int* scrI, bool& ok,
    float& d0, float& d1, float& d2, float& d3) {
  unsigned qmask = 0u;
  int qg = 0;
  #pragma unroll
  for (int m = 0; m < 8; ++m) {
    const bool q = gm[m] <= thr;
    qmask |= q ? (1u << m) : 0u;
    qg += q ? 1 : 0;
  }
  // Exclusive prefix + total of qg (0..8) via bit-plane ballots.
  const unsigned long long b0 = __ballot((qg & 1) != 0);
  const unsigned long long b1 = __ballot((qg & 2) != 0);
  const unsigned long long b2 = __ballot((qg & 4) != 0);
  const unsigned long long b3 = __ballot((qg & 8) != 0);
  const int pre =
      mbcnt64(b0) + 2 * mbcnt64(b1) + 4 * mbcnt64(b2) + 8 * mbcnt64(b3);
  const int tot = __popcll(b0) + 2 * __popcll(b1) + 4 * __popcll(b2) +
                  8 * __popcll(b3);
  ok = (tot <= 64);
  if (ok) {
    // Scatter qualifying group ids. Fast path: first 2 bits per lane
    // (wave-max qg <= 2 almost always); cold tail covers qg in [3,8].
    int pos = pre;
    unsigned mrem = qmask;
    #pragma unroll
    for (int k = 0; k < 2; ++k) {
      const bool w = (mrem != 0u);
      const int m = __ffs(mrem) - 1;
      if (w) scrI[pos] = (lane << 3) | m;
      pos += w ? 1 : 0;
      mrem = w ? (mrem & (mrem - 1u)) : 0u;
    }
    if (__ballot(mrem != 0u) != 0ull) {  // wave-uniform, rare
      #pragma unroll
      for (int k = 0; k < 6; ++k) {
        const bool w = (mrem != 0u);
        const int m = __ffs(mrem) - 1;
        if (w) scrI[pos] = (lane << 3) | m;
        pos += w ? 1 : 0;
        mrem = w ? (mrem & (mrem - 1u)) : 0u;
      }
    }
  }
  d0 = INFINITY; d1 = INFINITY; d2 = INFINITY; d3 = INFINITY;
  if (ok && lane < tot) {
    const int id = scrI[lane];
    const int o = ((id >> 3) << 2) + ((id & 7) << 8);
    const float4 cx4 = *(const float4*)&xs[o];
    const float4 cy4 = *(const float4*)&ys[o];
    const float4 cz4 = *(const float4*)&zs[o];
    d0 = dist2(px, py, pz, cx4.x, cy4.x, cz4.x);
    d1 = dist2(px, py, pz, cx4.y, cy4.y, cz4.y);
    d2 = dist2(px, py, pz, cx4.z, cy4.z, cz4.z);
    d3 = dist2(px, py, pz, cx4.w, cy4.w, cz4.w);
  }
}

// Exact fallback (~never): 16 extraction rounds, recompute from LDS.
__device__ float fallback_sum16(float px, float py, float pz, int lane,
                                const float* xs, const float* ys,
                                const float* zs) {
  float s = 0.f;
  unsigned consumed = 0u;
  #pragma unroll 1
  for (int r = 0; r < KSEL; ++r) {
    float bv = INFINITY;
    int bi = 0;
    #pragma unroll
    for (int m = 0; m < 8; ++m) {
      const int o = (lane << 2) + (m << 8);
      const float4 cx4 = *(const float4*)&xs[o];
      const float4 cy4 = *(const float4*)&ys[o];
      const float4 cz4 = *(const float4*)&zs[o];
      float dd;
      bool okb;
      dd = dist2(px, py, pz, cx4.x, cy4.x, cz4.x);
      okb = (((consumed >> ((m << 2) + 0)) & 1u) == 0u) && (dd < bv);
      bv = okb ? dd : bv; bi = okb ? ((m << 2) + 0) : bi;
      dd = dist2(px, py, pz, cx4.y, cy4.y, cz4.y);
      okb = (((consumed >> ((m << 2) + 1)) & 1u) == 0u) && (dd < bv);
      bv = okb ? dd : bv; bi = okb ? ((m << 2) + 1) : bi;
      dd = dist2(px, py, pz, cx4.z, cy4.z, cz4.z);
      okb = (((consumed >> ((m << 2) + 2)) & 1u) == 0u) && (dd < bv);
      bv = okb ? dd : bv; bi = okb ? ((m << 2) + 2) : bi;
      dd = dist2(px, py, pz, cx4.w, cy4.w, cz4.w);
      okb = (((consumed >> ((m << 2) + 3)) & 1u) == 0u) && (dd < bv);
      bv = okb ? dd : bv; bi = okb ? ((m << 2) + 3) : bi;
    }
    int bl = lane;
    #pragma unroll
    for (int ofs = 32; ofs >= 1; ofs >>= 1) {
      float ov = __shfl_xor(bv, ofs);
      int ol = __shfl_xor(bl, ofs);
      bool take = (ov < bv) || (ov == bv && ol < bl);
      bv = take ? ov : bv;
      bl = take ? ol : bl;
    }
    s += bv;
    if (lane == bl) consumed |= (1u << bi);
  }
  return s;
}

// Process one 16-query work item (group g): this wave's two queries.
// Returns sumA+sumB. scrI0/scrI1 are this wave's private 64-entry scratches.
__device__ float item_pair_sum(int g, int wave, int lane, const float* xs,
                               const float* ys, const float* zs, int* scrI0,
                               int* scrI1) {
  const int iA = g * PTS_PER_ITEM + wave * 2;
  const int iB = iA + 1;
  const float pax = xs[iA], pay = ys[iA], paz = zs[iA];
  const float pbx = xs[iB], pby = ys[iB], pbz = zs[iB];

  // Distance pass: candidate index = 4*lane + j + 256*m. Keep group mins.
  float gmA[8], gmB[8];
  #pragma unroll
  for (int m = 0; m < 8; ++m) {
    const int o = (lane << 2) + (m << 8);
    const float4 cx4 = *(const float4*)&xs[o];
    const float4 cy4 = *(const float4*)&ys[o];
    const float4 cz4 = *(const float4*)&zs[o];
    float a0 = dist2(pax, pay, paz, cx4.x, cy4.x, cz4.x);
    float a1 = dist2(pax, pay, paz, cx4.y, cy4.y, cz4.y);
    float a2 = dist2(pax, pay, paz, cx4.z, cy4.z, cz4.z);
    float a3 = dist2(pax, pay, paz, cx4.w, cy4.w, cz4.w);
    gmA[m] = fminf(fminf(a0, a1), fminf(a2, a3));
    float b0 = dist2(pbx, pby, pbz, cx4.x, cy4.x, cz4.x);
    float b1 = dist2(pbx, pby, pbz, cx4.y, cy4.y, cz4.y);
    float b2 = dist2(pbx, pby, pbz, cx4.z, cy4.z, cz4.z);
    float b3 = dist2(pbx, pby, pbz, cx4.w, cy4.w, cz4.w);
    gmB[m] = fminf(fminf(b0, b1), fminf(b2, b3));
  }
  float lminA = gmA[0], lminB = gmB[0];
  #pragma unroll
  for (int m = 1; m < 8; ++m) {
    lminA = fminf(lminA, gmA[m]);
    lminB = fminf(lminB, gmB[m]);
  }

  // Threshold bisection on lane-mins (uint-order-isomorphic for nonneg
  // floats), interleaved A/B, early-exit when count lands in [16,24].
  // Bounds seeded [1/512, 0.25] with guard ballots; invariants preserved:
  // count(<=hi) >= 16 always, count(<=lo) < 16 always.
  const unsigned uA = __float_as_uint(lminA);
  const unsigned uB = __float_as_uint(lminB);
  const unsigned SH = 0x3E800000u;  // 0.25f
  const unsigned SL = 0x3B000000u;  // 1/512
  unsigned loA = 0u, hiA = 0x7F800000u, loB = 0u, hiB = 0x7F800000u;
  bool thA = false, thB = false;
  {
    const int cA = __popcll(__ballot(uA <= SH));
    const int cB = __popcll(__ballot(uB <= SH));
    if (cA >= KSEL) { hiA = SH; thA = (cA <= 24); }
    if (cB >= KSEL) { hiB = SH; thB = (cB <= 24); }
    const int dA = __popcll(__ballot(uA <= SL));
    const int dB = __popcll(__ballot(uB <= SL));
    if (dA < KSEL) loA = SL;
    if (dB < KSEL) loB = SL;
  }
  #pragma unroll 1
  for (int r = 0; r < 16; ++r) {
    if (thA && thB) break;  // wave-uniform
    const unsigned midA = (loA + hiA) >> 1;
    const unsigned midB = (loB + hiB) >> 1;
    const int cA = __popcll(__ballot(uA <= midA));
    const int cB = __popcll(__ballot(uB <= midB));
    if (!thA) {
      const bool gA = cA >= KSEL;
      hiA = gA ? midA : hiA;
      loA = gA ? loA : midA;
      thA = (cA >= KSEL) && (cA <= 24);
    }
    if (!thB) {
      const bool gB = cB >= KSEL;
      hiB = gB ? midB : hiB;
      loB = gB ? loB : midB;
      thB = (cB >= KSEL) && (cB <= 24);
    }
  }
  const float thrA = __uint_as_float(hiA);
  const float thrB = __uint_as_float(hiB);

  // Gather candidates: <=4 register distances per lane per query. Candidate
  // multiset contains every distance <= thr (>=16 of them), so its 16
  // smallest equal the true 16 smallest.
  bool okA, okB;
  float a0, a1, a2, a3, b0, b1, b2, b3;
  gather_candidates(gmA, thrA, pax, pay, paz, lane, xs, ys, zs, scrI0, okA,
                    a0, a1, a2, a3);
  gather_candidates(gmB, thrB, pbx, pby, pbz, lane, xs, ys, zs, scrI1, okB,
                    b0, b1, b2, b3);

  // Exact 16-smallest sum via interleaved early-exit bit bisection on
  // w = bits(d)+1 (monotone; w>=1; INF -> 0x7F800001).
  // Seeds: ehi = bits(thr)+1 (count >= 16 guaranteed by gather
  // completeness); elo = bits(thr) - 6 exponent steps, guarded.
  // Exit when count==16 (sum values w <= mid directly) or hi == lo+1
  // (t* = value(hi-1); sum = sum(w<=lo) + (16 - count(w<=lo)) * t*).
  const unsigned wa0 = __float_as_uint(a0) + 1u, wa1 = __float_as_uint(a1) + 1u;
  const unsigned wa2 = __float_as_uint(a2) + 1u, wa3 = __float_as_uint(a3) + 1u;
  const unsigned wb0 = __float_as_uint(b0) + 1u, wb1 = __float_as_uint(b1) + 1u;
  const unsigned wb2 = __float_as_uint(b2) + 1u, wb3 = __float_as_uint(b3) + 1u;
  unsigned eloA = 0u, ehiA = hiA + 1u;
  unsigned eloB = 0u, ehiB = hiB + 1u;
  {
    const unsigned esA = (hiA >= (6u << 23)) ? hiA - (6u << 23) : 0u;
    const unsigned esB = (hiB >= (6u << 23)) ? hiB - (6u << 23) : 0u;
    const int nA = __popcll(__ballot(wa0 <= esA)) +
                   __popcll(__ballot(wa1 <= esA)) +
                   __popcll(__ballot(wa2 <= esA)) +
                   __popcll(__ballot(wa3 <= esA));
    const int nB = __popcll(__ballot(wb0 <= esB)) +
                   __popcll(__ballot(wb1 <= esB)) +
                   __popcll(__ballot(wb2 <= esB)) +
                   __popcll(__ballot(wb3 <= esB));
    if (nA < KSEL) eloA = esA;
    if (nB < KSEL) eloB = esB;
  }
  bool hA = false, hB = false;      // hit count==16 (sum directly via sel)
  unsigned sA = 0u, sB = 0u;
  #pragma unroll 1
  for (int r = 0; r < 32; ++r) {
    const bool needA = okA && !hA && (ehiA > eloA + 1u);
    const bool needB = okB && !hB && (ehiB > eloB + 1u);
    if (!(needA || needB)) break;  // wave-uniform
    const unsigned midA = (eloA + ehiA) >> 1;
    const unsigned midB = (eloB + ehiB) >> 1;
    const int cA = __popcll(__ballot(wa0 <= midA)) +
                   __popcll(__ballot(wa1 <= midA)) +
                   __popcll(__ballot(wa2 <= midA)) +
                   __popcll(__ballot(wa3 <= midA));
    const int cB = __popcll(__ballot(wb0 <= midB)) +
                   __popcll(__ballot(wb1 <= midB)) +
                   __popcll(__ballot(wb2 <= midB)) +
                   __popcll(__ballot(wb3 <= midB));
    if (needA) {
      if (cA >= KSEL) ehiA = midA; else eloA = midA;
      if (cA == KSEL) { hA = true; sA = midA; }
    }
    if (needB) {
      if (cB >= KSEL) ehiB = midB; else eloB = midB;
      if (cB == KSEL) { hB = true; sB = midB; }
    }
  }
  float extraA = 0.f, extraB = 0.f;
  if (okA && !hA) {
    sA = eloA;
    const int nlo = __popcll(__ballot(wa0 <= eloA)) +
                    __popcll(__ballot(wa1 <= eloA)) +
                    __popcll(__ballot(wa2 <= eloA)) +
                    __popcll(__ballot(wa3 <= eloA));
    extraA = (float)(KSEL - nlo) * __uint_as_float(ehiA - 1u);
  }
  if (okB && !hB) {
    sB = eloB;
    const int nlo = __popcll(__ballot(wb0 <= eloB)) +
                    __popcll(__ballot(wb1 <= eloB)) +
                    __popcll(__ballot(wb2 <= eloB)) +
                    __popcll(__ballot(wb3 <= eloB));
    extraB = (float)(KSEL - nlo) * __uint_as_float(ehiB - 1u);
  }
  float ca = 0.f, cb = 0.f;
  if (okA) {
    ca = ((wa0 <= sA) ? a0 : 0.f) + ((wa1 <= sA) ? a1 : 0.f) +
         ((wa2 <= sA) ? a2 : 0.f) + ((wa3 <= sA) ? a3 : 0.f);
  }
  if (okB) {
    cb = ((wb0 <= sB) ? b0 : 0.f) + ((wb1 <= sB) ? b1 : 0.f) +
         ((wb2 <= sB) ? b2 : 0.f) + ((wb3 <= sB) ? b3 : 0.f);
  }
  // Wave sums via DPP cascade (no DS-pipe traffic, no bpermute latency).
  const float caT = wave_sum_dpp(ca);
  const float cbT = wave_sum_dpp(cb);
  float sumA = caT + extraA;
  float sumB = cbT + extraB;
  if (!okA) sumA = fallback_sum16(pax, pay, paz, lane, xs, ys, zs);
  if (!okB) sumB = fallback_sum16(pbx, pby, pbz, lane, xs, ys, zs);
  return sumA + sumB;
}

__global__ __launch_bounds__(BLOCK) void knn_sum16_kernel(
    const float* __restrict__ seed, const float* __restrict__ gt,
    float* __restrict__ out_part) {
  __shared__ float xs[NPTS];
  __shared__ float ys[NPTS];
  __shared__ float zs[NPTS];
  __shared__ int scrI[WAVES_PER_BLOCK][2][64];
  __shared__ float bsums[WAVES_PER_BLOCK];

  const int bid = blockIdx.x;        // 1024 blocks (one full generation)
  const int t = bid >> 9;            // tensor: 0=seed 1=gt
  const int b = (bid >> 6) & 7;      // batch
  const int j = bid & 63;            // item-pair index: items 2j, 2j+1
  const float* base = (t == 0 ? seed : gt) + b * NPTS * 3;

  const int tid = threadIdx.x;

  // Stage SoA once for both items: thread tid handles points 4*tid..4*tid+3.
  {
    const float4* src = (const float4*)base;
    float4 f0 = src[3 * tid + 0];
    float4 f1 = src[3 * tid + 1];
    float4 f2 = src[3 * tid + 2];
    *(float4*)&xs[4 * tid] = make_float4(f0.x, f0.w, f1.z, f2.y);
    *(float4*)&ys[4 * tid] = make_float4(f0.y, f1.x, f1.w, f2.z);
    *(float4*)&zs[4 * tid] = make_float4(f0.z, f1.y, f2.x, f2.w);
  }
  __syncthreads();

  const int wave = tid >> 6;
  const int lane = tid & 63;

  // Two items back-to-back; scrI is wave-private so no barrier between.
  float wsum = item_pair_sum(2 * j + 0, wave, lane, xs, ys, zs,
                             &scrI[wave][0][0], &scrI[wave][1][0]);
  wsum += item_pair_sum(2 * j + 1, wave, lane, xs, ys, zs,
                        &scrI[wave][0][0], &scrI[wave][1][0]);

  if (lane == 0) bsums[wave] = wsum;
  __syncthreads();
  if (tid == 0) {
    float s = 0.f;
    #pragma unroll
    for (int w = 0; w < WAVES_PER_BLOCK; ++w) s += bsums[w];
    out_part[bid] = s;
  }
}

__global__ __launch_bounds__(1024) void final_reduce_kernel(
    const float* __restrict__ parts, float* __restrict__ out) {
  __shared__ float partial[16];
  const int tid = threadIdx.x;
  const int wave = tid >> 6;
  const int lane = tid & 63;
  // wave w reduces segment (t,b) = w: 64 block partials.
  float s = parts[wave * 64 + lane];
  #pragma unroll
  for (int ofs = 32; ofs >= 1; ofs >>= 1) s += __shfl_xor(s, ofs);
  if (lane == 0) partial[wave] = s;
  __syncthreads();
  if (tid == 0) {
    const float scale = 1.f / (2048.f * 16.f);  // mean over points, mean over k
    float acc = 0.f;
    #pragma unroll
    for (int bb = 0; bb < 8; ++bb) {
      float diff = (partial[bb] - partial[8 + bb]) * scale;
      acc += diff * diff;
    }
    out[0] = acc * 0.125f;
  }
}

extern "C" void kernel_launch(void* const* d_in, const int* in_sizes, int n_in,
                              void* d_out, int out_size, void* d_ws, size_t ws_size,
                              hipStream_t stream) {
  const float* seed = (const float*)d_in[0];
  const float* gt = (const float*)d_in[1];
  float* out = (float*)d_out;
  float* ws = (float*)d_ws;  // needs 1024 floats = 4 KB

  knn_sum16_kernel<<<NBLOCKS, BLOCK, 0, stream>>>(seed, gt, ws);
  final_reduce_kernel<<<1, 1024, 0, stream>>>(ws, out);
}